// Round 2
// baseline (324.680 us; speedup 1.0000x reference)
//
#include <hip/hip_runtime.h>

namespace {

constexpr int H  = 1080;
constexpr int W  = 1920;
constexpr int OH = 270;    // ceil(0.25 * 1080)
constexpr int OW = 480;    // ceil(0.25 * 1920)
constexpr int KT = 16;     // taps per output
constexpr int G  = 2;      // output rows per block; oh 2..267 in 133 chunks
constexpr int NCHUNK = 133;
constexpr int ROWS = 4 * G + 12;   // 20 input rows per block
constexpr int VSTRIDE = 1032;      // vbuf row stride in floats

constexpr int EDGE_FULL = 4 * OW;                    // 1920
constexpr int EDGE_TOT  = EDGE_FULL + (OH - 4) * 4;  // 2984
constexpr int EDGE_YS   = 6;   // 6 y-slices x 2 x-blocks x 256 = 3072 >= 2984

// ---------------------------------------------------------------------------
// Fused kernel.
//  by <  EDGE_YS : edge pixels (table-driven gather) — dispatched FIRST so
//                  their latency chains overlap interior work (no tail).
//  by >= EDGE_YS : interior tile.
//
// R6 MLP fix (R7 = infra retry of R6, source identical): previous build
// emitted load->vmcnt(0)->fma per row (VGPR=60, allocator targeted 8
// waves/SIMD), serializing 20 HBM latencies per block (~10us block lifetime,
// 2.1 TB/s). Now: ALL 20 row loads issue into a named v[ROWS][4] register
// batch, sched_barrier(0) pins the load/compute boundary,
// __launch_bounds__(256,4) raises the VGPR cap to 128 (4 waves/SIMD,
// 16 waves/CU). Expect ~1 latency per block -> BW-bound.
// ---------------------------------------------------------------------------
__global__ __launch_bounds__(256, 4) void bicubic_fused(
    const float* __restrict__ x,    // [BC, H, W]
    const float* __restrict__ wh,   // [OH, KT]
    const int*   __restrict__ ih,   // [OH, KT]
    const float* __restrict__ ww,   // [OW, KT]
    const int*   __restrict__ iw,   // [OW, KT]
    float*       __restrict__ out)  // [BC, OH, OW]
{
    __shared__ float vbuf[G * VSTRIDE];   // 8.3 KB

    const int tid = threadIdx.x;
    const int bx  = blockIdx.x;
    const int by  = blockIdx.y;
    const int bc  = blockIdx.z;

    if (by < EDGE_YS) {
        // ---------------- edge path ----------------
        const int idx = (by * 2 + bx) * 256 + tid;
        if (idx >= EDGE_TOT) return;

        int oh, ow;
        if (idx < EDGE_FULL) {
            int q = idx / OW;
            ow = idx - q * OW;
            oh = (q < 2) ? q : OH - 4 + q;
        } else {
            int t = idx - EDGE_FULL;
            int q = t & 3;
            oh = 2 + (t >> 2);
            ow = (q < 2) ? q : OW - 4 + q;
        }

        const float* __restrict__ img = x + (size_t)bc * ((size_t)H * W);

        float wt[KT];
        __builtin_memcpy(wt, ww + (size_t)ow * KT, sizeof(wt));
        int ir[KT];
        __builtin_memcpy(ir, iw + (size_t)ow * KT, sizeof(ir));

        bool fastc = true;
        #pragma unroll
        for (int k = 1; k < KT; ++k) fastc = fastc && (ir[k] == ir[0] + k);
        const int i0 = ir[0];

        float acc = 0.0f;
        #pragma unroll
        for (int kh = 0; kh < KT; ++kh) {
            const int   r = ih[oh * KT + kh];
            const float w = wh[oh * KT + kh];
            const float* row = img + (size_t)r * W;
            float h = 0.0f;
            if (fastc) {
                float v[KT];
                __builtin_memcpy(v, row + i0, sizeof(v));
                #pragma unroll
                for (int k = 0; k < KT; ++k) h = fmaf(v[k], wt[k], h);
            } else {
                #pragma unroll
                for (int k = 0; k < KT; ++k) h = fmaf(row[ir[k]], wt[k], h);
            }
            acc = fmaf(w, h, acc);
        }
        out[((size_t)bc * OH + oh) * OW + ow] = acc;
        return;
    }

    // ---------------- interior path ----------------
    const int owb = bx ? 254 : 2;       // output-col tile base
    const int Nw  = bx ? 224 : 252;     // outputs in this tile
    const int c0  = 4 * owb - 8;        // staged col base: 0 / 1008 (16B-aligned)
    const int oh0 = 2 + G * (by - EDGE_YS);   // 2..266
    const int r0  = 4 * oh0 - 6;

    // vertical weights (interior rows identical; oh0 wave-uniform -> s_load)
    float wr[KT];
    __builtin_memcpy(wr, wh + (size_t)oh0 * KT, sizeof(wr));

    // this thread's 4 input columns (16B-aligned; clamped dups land in LDS
    // slots never read by a valid output)
    int c = c0 + 4 * tid;
    if (c > W - 4) c = W - 4;
    const float* __restrict__ p =
        x + ((size_t)bc * H + (size_t)r0) * W + c;

    // --- phase 1: issue ALL 20 independent row loads (no consumer between) --
    float v[ROWS][4];
    #pragma unroll
    for (int r = 0; r < ROWS; ++r)
        __builtin_memcpy(v[r], p + (size_t)r * W, 16);

    // pin the load/compute boundary: scheduler may not sink loads past here
    __builtin_amdgcn_sched_barrier(0);

    // --- phase 2: vertical reduce into 2 accumulator sets --------------------
    // out row 0 uses input rows 0..15, out row 1 uses rows 4..19
    float a0[4] = {0.f, 0.f, 0.f, 0.f};
    float a1[4] = {0.f, 0.f, 0.f, 0.f};
    #pragma unroll
    for (int r = 0; r < 16; ++r) {
        const float w = wr[r];
        #pragma unroll
        for (int cc = 0; cc < 4; ++cc) a0[cc] = fmaf(w, v[r][cc], a0[cc]);
    }
    #pragma unroll
    for (int r = 4; r < ROWS; ++r) {
        const float w = wr[r - 4];
        #pragma unroll
        for (int cc = 0; cc < 4; ++cc) a1[cc] = fmaf(w, v[r][cc], a1[cc]);
    }

    // staged col c0+4t lives at LDS index 4t+2 (8B-aligned b64 writes)
    __builtin_memcpy(&vbuf[0 * VSTRIDE + 4 * tid + 2], a0, 16);
    __builtin_memcpy(&vbuf[1 * VSTRIDE + 4 * tid + 2], a1, 16);
    __syncthreads();

    // -------- horizontal: window for ow=owb+t starts at LDS 4t+4 (16B) ------
    if (tid < Nw) {
        const int ow = owb + tid;
        float wt[KT];
        __builtin_memcpy(wt, ww + (size_t)ow * KT, sizeof(wt));
        float* __restrict__ obase =
            out + ((size_t)bc * OH + oh0) * OW + ow;
        #pragma unroll
        for (int t = 0; t < G; ++t) {
            float vv[KT];
            __builtin_memcpy(vv, &vbuf[t * VSTRIDE + 4 * tid + 4], sizeof(vv));
            float s0 = 0.f, s1 = 0.f;
            #pragma unroll
            for (int k = 0; k < KT; k += 2) {
                s0 = fmaf(vv[k],     wt[k],     s0);
                s1 = fmaf(vv[k + 1], wt[k + 1], s1);
            }
            obase[(size_t)t * OW] = s0 + s1;
        }
    }
}

// ---------------------------------------------------------------------------
// Safety net for unexpected tap counts.
// ---------------------------------------------------------------------------
__global__ __launch_bounds__(256) void bicubic_generic(
    const float* __restrict__ x,
    const float* __restrict__ wh,
    const int*   __restrict__ ih,
    const float* __restrict__ ww,
    const int*   __restrict__ iw,
    float*       __restrict__ out,
    int Kh, int Kw, int total)
{
    int t = blockIdx.x * blockDim.x + threadIdx.x;
    if (t >= total) return;
    int ow = t % OW;
    int oh = (t / OW) % OH;
    int bc = t / (OW * OH);
    const float* img = x + (size_t)bc * ((size_t)H * W);
    float acc = 0.0f;
    for (int kh = 0; kh < Kh; ++kh) {
        const int   r = ih[oh * Kh + kh];
        const float w = wh[oh * Kh + kh];
        const float* row = img + (size_t)r * W;
        float h = 0.0f;
        for (int k = 0; k < Kw; ++k)
            h = fmaf(row[iw[ow * Kw + k]], ww[ow * Kw + k], h);
        acc = fmaf(w, h, acc);
    }
    out[t] = acc;
}

} // namespace

extern "C" void kernel_launch(void* const* d_in, const int* in_sizes, int n_in,
                              void* d_out, int out_size, void* d_ws, size_t ws_size,
                              hipStream_t stream) {
    const float* x  = (const float*)d_in[0];
    const float* wh = (const float*)d_in[1];
    const int*   ih = (const int*)d_in[2];
    const float* ww = (const float*)d_in[3];
    const int*   iw = (const int*)d_in[4];
    float*       out = (float*)d_out;

    const int BC = in_sizes[0] / (H * W);   // 24
    const int Kh = in_sizes[1] / OH;
    const int Kw = in_sizes[3] / OW;

    if (Kh == KT && Kw == KT) {
        dim3 grid(2, EDGE_YS + NCHUNK, BC);
        bicubic_fused<<<grid, 256, 0, stream>>>(x, wh, ih, ww, iw, out);
    } else {
        int total = BC * OH * OW;
        bicubic_generic<<<(total + 255) / 256, 256, 0, stream>>>(
            x, wh, ih, ww, iw, out, Kh, Kw, total);
    }
}

// Round 3
// 323.283 us; speedup vs baseline: 1.0043x; 1.0043x over previous
//
#include <hip/hip_runtime.h>

namespace {

constexpr int H  = 1080;
constexpr int W  = 1920;
constexpr int OH = 270;    // ceil(0.25 * 1080)
constexpr int OW = 480;    // ceil(0.25 * 1920)
constexpr int KT = 16;     // taps per output
constexpr int G  = 2;      // output rows per block; oh 2..267 in 133 chunks
constexpr int NCHUNK = 133;
constexpr int ROWS = 4 * G + 12;   // 20 input rows per block
constexpr int VSTRIDE = 1032;      // vbuf row stride in floats

constexpr int EDGE_FULL = 4 * OW;                    // 1920
constexpr int EDGE_TOT  = EDGE_FULL + (OH - 4) * 4;  // 2984
constexpr int EDGE_YS   = 6;   // 6 y-slices x 2 x-blocks x 256 = 3072 >= 2984

typedef float vf4 __attribute__((ext_vector_type(4)));

// ---------------------------------------------------------------------------
// Fused kernel.
//  by <  EDGE_YS : edge pixels (table-driven gather).
//  by >= EDGE_YS : interior tile.
//
// R8: C++-level load batching (R6/R7) produced ZERO codegen delta (VGPR
// stayed 60, loads re-serialized by the max-occupancy scheduler). Now the
// 20 row loads are ONE volatile asm block in saddr form:
//   global_load_dwordx4 vdst, voff, s[base:+1]  ;  voff += 0x1e00 (7680B)
// 20 early-clobber "=&v" vf4 outputs force 80 result VGPRs live -> the HW
// must hold 20 loads in flight -> 1 HBM latency per block instead of 20.
// Expect BW-bound: ~278 MB/dispatch at >=5 TB/s ~= 50 us.
// ---------------------------------------------------------------------------
__global__ __launch_bounds__(256, 4) void bicubic_fused(
    const float* __restrict__ x,    // [BC, H, W]
    const float* __restrict__ wh,   // [OH, KT]
    const int*   __restrict__ ih,   // [OH, KT]
    const float* __restrict__ ww,   // [OW, KT]
    const int*   __restrict__ iw,   // [OW, KT]
    float*       __restrict__ out)  // [BC, OH, OW]
{
    __shared__ float vbuf[G * VSTRIDE];   // 8.3 KB

    const int tid = threadIdx.x;
    const int bx  = blockIdx.x;
    const int by  = blockIdx.y;
    const int bc  = blockIdx.z;

    if (by < EDGE_YS) {
        // ---------------- edge path ----------------
        const int idx = (by * 2 + bx) * 256 + tid;
        if (idx >= EDGE_TOT) return;

        int oh, ow;
        if (idx < EDGE_FULL) {
            int q = idx / OW;
            ow = idx - q * OW;
            oh = (q < 2) ? q : OH - 4 + q;
        } else {
            int t = idx - EDGE_FULL;
            int q = t & 3;
            oh = 2 + (t >> 2);
            ow = (q < 2) ? q : OW - 4 + q;
        }

        const float* __restrict__ img = x + (size_t)bc * ((size_t)H * W);

        float wt[KT];
        __builtin_memcpy(wt, ww + (size_t)ow * KT, sizeof(wt));
        int ir[KT];
        __builtin_memcpy(ir, iw + (size_t)ow * KT, sizeof(ir));

        bool fastc = true;
        #pragma unroll
        for (int k = 1; k < KT; ++k) fastc = fastc && (ir[k] == ir[0] + k);
        const int i0 = ir[0];

        float acc = 0.0f;
        #pragma unroll
        for (int kh = 0; kh < KT; ++kh) {
            const int   r = ih[oh * KT + kh];
            const float w = wh[oh * KT + kh];
            const float* row = img + (size_t)r * W;
            float h = 0.0f;
            if (fastc) {
                float v[KT];
                __builtin_memcpy(v, row + i0, sizeof(v));
                #pragma unroll
                for (int k = 0; k < KT; ++k) h = fmaf(v[k], wt[k], h);
            } else {
                #pragma unroll
                for (int k = 0; k < KT; ++k) h = fmaf(row[ir[k]], wt[k], h);
            }
            acc = fmaf(w, h, acc);
        }
        out[((size_t)bc * OH + oh) * OW + ow] = acc;
        return;
    }

    // ---------------- interior path ----------------
    const int owb = bx ? 254 : 2;       // output-col tile base
    const int Nw  = bx ? 224 : 252;     // outputs in this tile
    const int c0  = 4 * owb - 8;        // staged col base: 0 / 1008 (16B-aligned)
    const int oh0 = 2 + G * (by - EDGE_YS);   // 2..266
    const int r0  = 4 * oh0 - 6;        // 2..1058; r0+19 <= 1077 < H

    // vertical weights (interior rows identical; oh0 wave-uniform -> s_load,
    // so wr[] lives in SGPRs and costs no VGPRs as the FMA scalar operand)
    float wr[KT];
    __builtin_memcpy(wr, wh + (size_t)oh0 * KT, sizeof(wr));

    // this thread's 4 input columns (16B-aligned; clamped dups land in LDS
    // slots never read by a valid output)
    int c = c0 + 4 * tid;
    if (c > W - 4) c = W - 4;

    // block-uniform row base (SGPR pair) + per-thread byte offset (1 VGPR)
    const float* pbase = x + ((size_t)bc * H + (size_t)r0) * W;
    unsigned voff = (unsigned)(4 * c);

    // --- phase 1: ALL 20 row loads in ONE asm block: forced MLP ------------
    vf4 o0, o1, o2, o3, o4, o5, o6, o7, o8, o9,
        o10, o11, o12, o13, o14, o15, o16, o17, o18, o19;
    asm volatile(
        "global_load_dwordx4 %[o0], %[off], %[base]\n\t"
        "v_add_u32 %[off], 0x1e00, %[off]\n\t"
        "global_load_dwordx4 %[o1], %[off], %[base]\n\t"
        "v_add_u32 %[off], 0x1e00, %[off]\n\t"
        "global_load_dwordx4 %[o2], %[off], %[base]\n\t"
        "v_add_u32 %[off], 0x1e00, %[off]\n\t"
        "global_load_dwordx4 %[o3], %[off], %[base]\n\t"
        "v_add_u32 %[off], 0x1e00, %[off]\n\t"
        "global_load_dwordx4 %[o4], %[off], %[base]\n\t"
        "v_add_u32 %[off], 0x1e00, %[off]\n\t"
        "global_load_dwordx4 %[o5], %[off], %[base]\n\t"
        "v_add_u32 %[off], 0x1e00, %[off]\n\t"
        "global_load_dwordx4 %[o6], %[off], %[base]\n\t"
        "v_add_u32 %[off], 0x1e00, %[off]\n\t"
        "global_load_dwordx4 %[o7], %[off], %[base]\n\t"
        "v_add_u32 %[off], 0x1e00, %[off]\n\t"
        "global_load_dwordx4 %[o8], %[off], %[base]\n\t"
        "v_add_u32 %[off], 0x1e00, %[off]\n\t"
        "global_load_dwordx4 %[o9], %[off], %[base]\n\t"
        "v_add_u32 %[off], 0x1e00, %[off]\n\t"
        "global_load_dwordx4 %[o10], %[off], %[base]\n\t"
        "v_add_u32 %[off], 0x1e00, %[off]\n\t"
        "global_load_dwordx4 %[o11], %[off], %[base]\n\t"
        "v_add_u32 %[off], 0x1e00, %[off]\n\t"
        "global_load_dwordx4 %[o12], %[off], %[base]\n\t"
        "v_add_u32 %[off], 0x1e00, %[off]\n\t"
        "global_load_dwordx4 %[o13], %[off], %[base]\n\t"
        "v_add_u32 %[off], 0x1e00, %[off]\n\t"
        "global_load_dwordx4 %[o14], %[off], %[base]\n\t"
        "v_add_u32 %[off], 0x1e00, %[off]\n\t"
        "global_load_dwordx4 %[o15], %[off], %[base]\n\t"
        "v_add_u32 %[off], 0x1e00, %[off]\n\t"
        "global_load_dwordx4 %[o16], %[off], %[base]\n\t"
        "v_add_u32 %[off], 0x1e00, %[off]\n\t"
        "global_load_dwordx4 %[o17], %[off], %[base]\n\t"
        "v_add_u32 %[off], 0x1e00, %[off]\n\t"
        "global_load_dwordx4 %[o18], %[off], %[base]\n\t"
        "v_add_u32 %[off], 0x1e00, %[off]\n\t"
        "global_load_dwordx4 %[o19], %[off], %[base]\n\t"
        "s_waitcnt vmcnt(0)"
        : [o0]"=&v"(o0), [o1]"=&v"(o1), [o2]"=&v"(o2), [o3]"=&v"(o3),
          [o4]"=&v"(o4), [o5]"=&v"(o5), [o6]"=&v"(o6), [o7]"=&v"(o7),
          [o8]"=&v"(o8), [o9]"=&v"(o9), [o10]"=&v"(o10), [o11]"=&v"(o11),
          [o12]"=&v"(o12), [o13]"=&v"(o13), [o14]"=&v"(o14), [o15]"=&v"(o15),
          [o16]"=&v"(o16), [o17]"=&v"(o17), [o18]"=&v"(o18), [o19]"=&v"(o19),
          [off]"+v"(voff)
        : [base]"s"(pbase)
        : "memory");

    // --- phase 2: vertical reduce into 2 accumulator sets ------------------
    // out row 0 uses input rows 0..15, out row 1 uses rows 4..19
    float a0[4] = {0.f, 0.f, 0.f, 0.f};
    float a1[4] = {0.f, 0.f, 0.f, 0.f};

    #define ACC0(r) { const float w = wr[r];                      \
        a0[0] = fmaf(w, o##r[0], a0[0]);                          \
        a0[1] = fmaf(w, o##r[1], a0[1]);                          \
        a0[2] = fmaf(w, o##r[2], a0[2]);                          \
        a0[3] = fmaf(w, o##r[3], a0[3]); }
    #define ACC1(r) { const float w = wr[(r) - 4];                \
        a1[0] = fmaf(w, o##r[0], a1[0]);                          \
        a1[1] = fmaf(w, o##r[1], a1[1]);                          \
        a1[2] = fmaf(w, o##r[2], a1[2]);                          \
        a1[3] = fmaf(w, o##r[3], a1[3]); }

    ACC0(0)  ACC0(1)  ACC0(2)  ACC0(3)
    ACC1(4)  ACC0(4)  ACC1(5)  ACC0(5)
    ACC1(6)  ACC0(6)  ACC1(7)  ACC0(7)
    ACC1(8)  ACC0(8)  ACC1(9)  ACC0(9)
    ACC1(10) ACC0(10) ACC1(11) ACC0(11)
    ACC1(12) ACC0(12) ACC1(13) ACC0(13)
    ACC1(14) ACC0(14) ACC1(15) ACC0(15)
    ACC1(16) ACC1(17) ACC1(18) ACC1(19)

    #undef ACC0
    #undef ACC1

    // staged col c0+4t lives at LDS index 4t+2 (8B-aligned b64 writes)
    __builtin_memcpy(&vbuf[0 * VSTRIDE + 4 * tid + 2], a0, 16);
    __builtin_memcpy(&vbuf[1 * VSTRIDE + 4 * tid + 2], a1, 16);
    __syncthreads();

    // -------- horizontal: window for ow=owb+t starts at LDS 4t+4 (16B) ------
    if (tid < Nw) {
        const int ow = owb + tid;
        float wt[KT];
        __builtin_memcpy(wt, ww + (size_t)ow * KT, sizeof(wt));
        float* __restrict__ obase =
            out + ((size_t)bc * OH + oh0) * OW + ow;
        #pragma unroll
        for (int t = 0; t < G; ++t) {
            float vv[KT];
            __builtin_memcpy(vv, &vbuf[t * VSTRIDE + 4 * tid + 4], sizeof(vv));
            float s0 = 0.f, s1 = 0.f;
            #pragma unroll
            for (int k = 0; k < KT; k += 2) {
                s0 = fmaf(vv[k],     wt[k],     s0);
                s1 = fmaf(vv[k + 1], wt[k + 1], s1);
            }
            obase[(size_t)t * OW] = s0 + s1;
        }
    }
}

// ---------------------------------------------------------------------------
// Safety net for unexpected tap counts.
// ---------------------------------------------------------------------------
__global__ __launch_bounds__(256) void bicubic_generic(
    const float* __restrict__ x,
    const float* __restrict__ wh,
    const int*   __restrict__ ih,
    const float* __restrict__ ww,
    const int*   __restrict__ iw,
    float*       __restrict__ out,
    int Kh, int Kw, int total)
{
    int t = blockIdx.x * blockDim.x + threadIdx.x;
    if (t >= total) return;
    int ow = t % OW;
    int oh = (t / OW) % OH;
    int bc = t / (OW * OH);
    const float* img = x + (size_t)bc * ((size_t)H * W);
    float acc = 0.0f;
    for (int kh = 0; kh < Kh; ++kh) {
        const int   r = ih[oh * Kh + kh];
        const float w = wh[oh * Kh + kh];
        const float* row = img + (size_t)r * W;
        float h = 0.0f;
        for (int k = 0; k < Kw; ++k)
            h = fmaf(row[iw[ow * Kw + k]], ww[ow * Kw + k], h);
        acc = fmaf(w, h, acc);
    }
    out[t] = acc;
}

} // namespace

extern "C" void kernel_launch(void* const* d_in, const int* in_sizes, int n_in,
                              void* d_out, int out_size, void* d_ws, size_t ws_size,
                              hipStream_t stream) {
    const float* x  = (const float*)d_in[0];
    const float* wh = (const float*)d_in[1];
    const int*   ih = (const int*)d_in[2];
    const float* ww = (const float*)d_in[3];
    const int*   iw = (const int*)d_in[4];
    float*       out = (float*)d_out;

    const int BC = in_sizes[0] / (H * W);   // 24
    const int Kh = in_sizes[1] / OH;
    const int Kw = in_sizes[3] / OW;

    if (Kh == KT && Kw == KT) {
        dim3 grid(2, EDGE_YS + NCHUNK, BC);
        bicubic_fused<<<grid, 256, 0, stream>>>(x, wh, ih, ww, iw, out);
    } else {
        int total = BC * OH * OW;
        bicubic_generic<<<(total + 255) / 256, 256, 0, stream>>>(
            x, wh, ih, ww, iw, out, Kh, Kw, total);
    }
}

// Round 4
// 321.629 us; speedup vs baseline: 1.0095x; 1.0051x over previous
//
#include <hip/hip_runtime.h>

namespace {

constexpr int H  = 1080;
constexpr int W  = 1920;
constexpr int OH = 270;    // ceil(0.25 * 1080)
constexpr int OW = 480;    // ceil(0.25 * 1920)
constexpr int KT = 16;     // taps per output
constexpr int GSEG = 14;   // output rows per interior block; 266 = 19*14 exactly
constexpr int NSEG = 19;
constexpr int RPB  = 4 * GSEG + 12;   // 68 input rows streamed per block
constexpr int DEPTH = 8;              // load-ring depth (vmcnt-counted)
constexpr int VSTRIDE = 1032;         // LDS row stride in floats

constexpr int EDGE_FULL = 4 * OW;                    // 1920
constexpr int EDGE_TOT  = EDGE_FULL + (OH - 4) * 4;  // 2984
constexpr int EDGE_YS   = 6;   // 6 y-slices x 2 x-blocks x 256 = 3072 >= 2984

typedef float vf4 __attribute__((ext_vector_type(4)));

__device__ __forceinline__ void fma4(vf4& a, float w, const vf4& v) {
    #pragma unroll
    for (int i = 0; i < 4; ++i) a[i] = fmaf(w, v[i], a[i]);
}

// One streaming load: dwordx4 at (pbase SGPR-pair + voff), then bump voff by
// one image row (0x1e00 = 7680 B). Same saddr form R3 proved to assemble/run.
__device__ __forceinline__ void issue_load(vf4& dst, unsigned& voff,
                                           const float* pbase) {
    asm volatile("global_load_dwordx4 %0, %1, %2\n\t"
                 "v_add_u32 %1, 0x1e00, %1"
                 : "=&v"(dst), "+v"(voff)
                 : "s"(pbase));
}

// Counted wait: allow N loads outstanding. sched_barrier stops the compiler
// from hoisting ring consumers above the wait (rule #18).
template<int N> __device__ __forceinline__ void wait_vmcnt() {
    static_assert(N >= 0 && N <= 7, "");
    if constexpr      (N == 0) asm volatile("s_waitcnt vmcnt(0)");
    else if constexpr (N == 1) asm volatile("s_waitcnt vmcnt(1)");
    else if constexpr (N == 2) asm volatile("s_waitcnt vmcnt(2)");
    else if constexpr (N == 3) asm volatile("s_waitcnt vmcnt(3)");
    else if constexpr (N == 4) asm volatile("s_waitcnt vmcnt(4)");
    else if constexpr (N == 5) asm volatile("s_waitcnt vmcnt(5)");
    else if constexpr (N == 6) asm volatile("s_waitcnt vmcnt(6)");
    else                       asm volatile("s_waitcnt vmcnt(7)");
    __builtin_amdgcn_sched_barrier(0);
}

// Close output row J: stage acc into LDS, raw barrier (NO vmcnt drain -> the
// global-load pipeline stays full; LDS data comes from registers, never from
// pending loads, so skipping the drain is safe), horizontal 16-tap, store.
// Buffer parity J&1; reuse at J+2 is ordered by the J+1 close's barrier.
__device__ __forceinline__ void do_close(int J, vf4& acc, float* vb,
    int tid, int Nw, const float (&wt)[KT], float* obase)
{
    __builtin_memcpy(vb + (J & 1) * VSTRIDE + 4 * tid + 2, &acc, 16);
    acc = vf4{0.f, 0.f, 0.f, 0.f};
    asm volatile("s_waitcnt lgkmcnt(0)" ::: "memory");
    __builtin_amdgcn_s_barrier();
    if (tid < Nw) {
        float vv[KT];
        __builtin_memcpy(vv, vb + (J & 1) * VSTRIDE + 4 * tid + 4, sizeof(vv));
        float s0 = 0.f, s1 = 0.f;
        #pragma unroll
        for (int k = 0; k < KT; k += 2) {
            s0 = fmaf(vv[k],     wt[k],     s0);
            s1 = fmaf(vv[k + 1], wt[k + 1], s1);
        }
        obase[(size_t)J * OW] = s0 + s1;
    }
}

// One streamed input row RR (fully static: ring slot, acc slots, weights,
// wait count, close point all compile-time).
template<int RR>
__device__ __forceinline__ void row_step(vf4 (&ring)[DEPTH], vf4 (&A)[4],
    unsigned& voff, const float* pbase, const float (&wr)[KT],
    float* vb, int tid, int Nw, const float (&wt)[KT], float* obase)
{
    constexpr int OUT = (RPB - 1 - RR) < 7 ? (RPB - 1 - RR) : 7;
    wait_vmcnt<OUT>();
    vf4 v = ring[RR & (DEPTH - 1)];
    if constexpr (RR + DEPTH < RPB)
        issue_load(ring[RR & (DEPTH - 1)], voff, pbase);

    constexpr int M = RR >> 2, Q = RR & 3;
    // input row RR feeds open output rows j = M-k (k=0..3), weight wr[Q+4k]
    if constexpr (M - 0 >= 0 && M - 0 <= GSEG - 1) fma4(A[(M - 0) & 3], wr[Q +  0], v);
    if constexpr (M - 1 >= 0 && M - 1 <= GSEG - 1) fma4(A[(M - 1) & 3], wr[Q +  4], v);
    if constexpr (M - 2 >= 0 && M - 2 <= GSEG - 1) fma4(A[(M - 2) & 3], wr[Q +  8], v);
    if constexpr (M - 3 >= 0 && M - 3 <= GSEG - 1) fma4(A[(M - 3) & 3], wr[Q + 12], v);

    if constexpr (Q == 3 && M >= 3 && (M - 3) <= GSEG - 1)
        do_close(M - 3, A[(M - 3) & 3], vb, tid, Nw, wt, obase);
}

template<int RR> struct RowsT {
    static __device__ __forceinline__ void run(vf4 (&ring)[DEPTH], vf4 (&A)[4],
        unsigned& voff, const float* pbase, const float (&wr)[KT],
        float* vb, int tid, int Nw, const float (&wt)[KT], float* obase)
    {
        row_step<RR>(ring, A, voff, pbase, wr, vb, tid, Nw, wt, obase);
        RowsT<RR + 1>::run(ring, A, voff, pbase, wr, vb, tid, Nw, wt, obase);
    }
};
template<> struct RowsT<RPB> {
    static __device__ __forceinline__ void run(vf4 (&)[DEPTH], vf4 (&)[4],
        unsigned&, const float*, const float (&)[KT],
        float*, int, int, const float (&)[KT], float*) {}
};

// ---------------------------------------------------------------------------
// R9: streaming rolling-window kernel.
// R3 post-mortem: 20-deep forced MLP per wave changed NOTHING (2.1 TB/s,
// 25% occupancy) -> per-wave MLP is not the constraint; the 2-row blocks
// (one load burst, barrier, tail, retire) cap effective concurrency.
// Now 912 interior blocks each stream 68 rows -> 14 output rows:
//  - depth-8 asm load ring, counted vmcnt(7) (T4), never drained at barriers
//  - 4 rolling acc sets; row r feeds 4 open outputs, weights wr[q+4k] static
//  - per-close: LDS stage (R0-proven layout) + raw s_barrier + horizontal
// Re-fetch overlap drops 12/20 -> 12/68; every wave holds ~8KB in flight
// for its whole lifetime.
// ---------------------------------------------------------------------------
__global__ __launch_bounds__(256, 4) void bicubic_fused(
    const float* __restrict__ x,    // [BC, H, W]
    const float* __restrict__ wh,   // [OH, KT]
    const int*   __restrict__ ih,   // [OH, KT]
    const float* __restrict__ ww,   // [OW, KT]
    const int*   __restrict__ iw,   // [OW, KT]
    float*       __restrict__ out)  // [BC, OH, OW]
{
    __shared__ float vbuf[2 * VSTRIDE];   // 8.3 KB ping-pong row buffers

    const int tid = threadIdx.x;
    const int bx  = blockIdx.x;
    const int by  = blockIdx.y;
    const int bc  = blockIdx.z;

    if (by < EDGE_YS) {
        // ---------------- edge path (unchanged, verified) ----------------
        const int idx = (by * 2 + bx) * 256 + tid;
        if (idx >= EDGE_TOT) return;

        int oh, ow;
        if (idx < EDGE_FULL) {
            int q = idx / OW;
            ow = idx - q * OW;
            oh = (q < 2) ? q : OH - 4 + q;
        } else {
            int t = idx - EDGE_FULL;
            int q = t & 3;
            oh = 2 + (t >> 2);
            ow = (q < 2) ? q : OW - 4 + q;
        }

        const float* __restrict__ img = x + (size_t)bc * ((size_t)H * W);

        float wt[KT];
        __builtin_memcpy(wt, ww + (size_t)ow * KT, sizeof(wt));
        int ir[KT];
        __builtin_memcpy(ir, iw + (size_t)ow * KT, sizeof(ir));

        bool fastc = true;
        #pragma unroll
        for (int k = 1; k < KT; ++k) fastc = fastc && (ir[k] == ir[0] + k);
        const int i0 = ir[0];

        float acc = 0.0f;
        #pragma unroll
        for (int kh = 0; kh < KT; ++kh) {
            const int   r = ih[oh * KT + kh];
            const float w = wh[oh * KT + kh];
            const float* row = img + (size_t)r * W;
            float h = 0.0f;
            if (fastc) {
                float v[KT];
                __builtin_memcpy(v, row + i0, sizeof(v));
                #pragma unroll
                for (int k = 0; k < KT; ++k) h = fmaf(v[k], wt[k], h);
            } else {
                #pragma unroll
                for (int k = 0; k < KT; ++k) h = fmaf(row[ir[k]], wt[k], h);
            }
            acc = fmaf(w, h, acc);
        }
        out[((size_t)bc * OH + oh) * OW + ow] = acc;
        return;
    }

    // ---------------- interior streaming path ----------------
    const int owb = bx ? 254 : 2;       // output-col tile base
    const int Nw  = bx ? 224 : 252;     // outputs in this tile
    const int c0  = 4 * owb - 8;        // staged col base: 0 / 1008
    const int seg = by - EDGE_YS;       // 0..18
    const int oh0 = 2 + GSEG * seg;     // 2..254
    const int r0  = 4 * oh0 - 6;        // 2..1010; r0+67 <= 1077 < H

    // vertical weights (interior rows identical -> one 16-entry table)
    float wr[KT];
    __builtin_memcpy(wr, wh + (size_t)oh0 * KT, sizeof(wr));

    // horizontal weights for this thread's output column (clamped dup load
    // for tid >= Nw; those threads never store)
    const int owc = (owb + tid < OW) ? (owb + tid) : (OW - 1);
    float wt[KT];
    __builtin_memcpy(wt, ww + (size_t)owc * KT, sizeof(wt));

    // this thread's 4 input columns (16B-aligned; clamped dups land in LDS
    // slots never read by a valid output)
    int c = c0 + 4 * tid;
    if (c > W - 4) c = W - 4;

    const float* pbase = x + ((size_t)bc * H + (size_t)r0) * W;
    unsigned voff = (unsigned)(4 * c);

    vf4 ring[DEPTH];
    vf4 A[4] = {vf4{0,0,0,0}, vf4{0,0,0,0}, vf4{0,0,0,0}, vf4{0,0,0,0}};

    #pragma unroll
    for (int i = 0; i < DEPTH; ++i) issue_load(ring[i], voff, pbase);

    float* obase = out + ((size_t)bc * OH + oh0) * OW + owb + tid;
    RowsT<0>::run(ring, A, voff, pbase, wr, vbuf, tid, Nw, wt, obase);
}

// ---------------------------------------------------------------------------
// Safety net for unexpected tap counts.
// ---------------------------------------------------------------------------
__global__ __launch_bounds__(256) void bicubic_generic(
    const float* __restrict__ x,
    const float* __restrict__ wh,
    const int*   __restrict__ ih,
    const float* __restrict__ ww,
    const int*   __restrict__ iw,
    float*       __restrict__ out,
    int Kh, int Kw, int total)
{
    int t = blockIdx.x * blockDim.x + threadIdx.x;
    if (t >= total) return;
    int ow = t % OW;
    int oh = (t / OW) % OH;
    int bc = t / (OW * OH);
    const float* img = x + (size_t)bc * ((size_t)H * W);
    float acc = 0.0f;
    for (int kh = 0; kh < Kh; ++kh) {
        const int   r = ih[oh * Kh + kh];
        const float w = wh[oh * Kh + kh];
        const float* row = img + (size_t)r * W;
        float h = 0.0f;
        for (int k = 0; k < Kw; ++k)
            h = fmaf(row[iw[ow * Kw + k]], ww[ow * Kw + k], h);
        acc = fmaf(w, h, acc);
    }
    out[t] = acc;
}

} // namespace

extern "C" void kernel_launch(void* const* d_in, const int* in_sizes, int n_in,
                              void* d_out, int out_size, void* d_ws, size_t ws_size,
                              hipStream_t stream) {
    const float* x  = (const float*)d_in[0];
    const float* wh = (const float*)d_in[1];
    const int*   ih = (const int*)d_in[2];
    const float* ww = (const float*)d_in[3];
    const int*   iw = (const int*)d_in[4];
    float*       out = (float*)d_out;

    const int BC = in_sizes[0] / (H * W);   // 24
    const int Kh = in_sizes[1] / OH;
    const int Kw = in_sizes[3] / OW;

    if (Kh == KT && Kw == KT) {
        dim3 grid(2, EDGE_YS + NSEG, BC);
        bicubic_fused<<<grid, 256, 0, stream>>>(x, wh, ih, ww, iw, out);
    } else {
        int total = BC * OH * OW;
        bicubic_generic<<<(total + 255) / 256, 256, 0, stream>>>(
            x, wh, ih, ww, iw, out, Kh, Kw, total);
    }
}

// Round 6
// 301.250 us; speedup vs baseline: 1.0778x; 1.0676x over previous
//
#include <hip/hip_runtime.h>

namespace {

constexpr int H  = 1080;
constexpr int W  = 1920;
constexpr int OH = 270;    // ceil(0.25 * 1080)
constexpr int OW = 480;    // ceil(0.25 * 1920)
constexpr int KT = 16;     // taps per output
constexpr int GSEG = 14;   // output rows per interior block; 266 = 19*14 exactly
constexpr int NSEG = 19;
constexpr int RPB  = 4 * GSEG + 12;   // 68 input rows streamed per block
constexpr int DEPTH = 8;              // load-ring depth (vmcnt-counted)
constexpr int VSTRIDE = 1032;         // LDS row stride in floats

constexpr int EDGE_FULL = 4 * OW;                    // 1920
constexpr int EDGE_TOT  = EDGE_FULL + (OH - 4) * 4;  // 2984
constexpr int EDGE_YS   = 6;   // 6 y-slices x 2 x-blocks x 256 = 3072 >= 2984

typedef float vf4 __attribute__((ext_vector_type(4)));

__device__ __forceinline__ void fma4(vf4& a, float w, const vf4& v) {
    #pragma unroll
    for (int i = 0; i < 4; ++i) a[i] = fmaf(w, v[i], a[i]);
}

// One streaming load: dwordx4 at (pbase SGPR-pair + voff), then bump voff by
// one image row (0x1e00 = 7680 B). Proven to assemble/run in R3/R4.
__device__ __forceinline__ void issue_load(vf4& dst, unsigned& voff,
                                           const float* pbase) {
    asm volatile("global_load_dwordx4 %0, %1, %2\n\t"
                 "v_add_u32 %1, 0x1e00, %1"
                 : "=&v"(dst), "+v"(voff)
                 : "s"(pbase));
}

// Counted wait: allow N loads outstanding. sched_barrier stops the compiler
// from hoisting ring consumers above the wait (rule #18).
template<int N> __device__ __forceinline__ void wait_vmcnt() {
    static_assert(N >= 0 && N <= 7, "");
    if constexpr      (N == 0) asm volatile("s_waitcnt vmcnt(0)");
    else if constexpr (N == 1) asm volatile("s_waitcnt vmcnt(1)");
    else if constexpr (N == 2) asm volatile("s_waitcnt vmcnt(2)");
    else if constexpr (N == 3) asm volatile("s_waitcnt vmcnt(3)");
    else if constexpr (N == 4) asm volatile("s_waitcnt vmcnt(4)");
    else if constexpr (N == 5) asm volatile("s_waitcnt vmcnt(5)");
    else if constexpr (N == 6) asm volatile("s_waitcnt vmcnt(6)");
    else                       asm volatile("s_waitcnt vmcnt(7)");
    __builtin_amdgcn_sched_barrier(0);
}

// Close output row J: stage acc into LDS, raw barrier (NO vmcnt drain -> the
// global-load pipeline stays full), horizontal 16-tap, store.
__device__ __forceinline__ void do_close(int J, vf4& acc, float* vb,
    int tid, int Nw, const float (&wt)[KT], float* obase)
{
    __builtin_memcpy(vb + (J & 1) * VSTRIDE + 4 * tid + 2, &acc, 16);
    acc = vf4{0.f, 0.f, 0.f, 0.f};
    asm volatile("s_waitcnt lgkmcnt(0)" ::: "memory");
    __builtin_amdgcn_s_barrier();
    if (tid < Nw) {
        float vv[KT];
        __builtin_memcpy(vv, vb + (J & 1) * VSTRIDE + 4 * tid + 4, sizeof(vv));
        float s0 = 0.f, s1 = 0.f;
        #pragma unroll
        for (int k = 0; k < KT; k += 2) {
            s0 = fmaf(vv[k],     wt[k],     s0);
            s1 = fmaf(vv[k + 1], wt[k + 1], s1);
        }
        obase[(size_t)J * OW] = s0 + s1;
    }
}

// One streamed input row RR (fully static indices).
template<int RR>
__device__ __forceinline__ void row_step(vf4 (&ring)[DEPTH], vf4 (&A)[4],
    unsigned& voff, const float* pbase, const float (&wr)[KT],
    float* vb, int tid, int Nw, const float (&wt)[KT], float* obase)
{
    constexpr int OUT = (RPB - 1 - RR) < 7 ? (RPB - 1 - RR) : 7;
    wait_vmcnt<OUT>();
    vf4 v = ring[RR & (DEPTH - 1)];
    if constexpr (RR + DEPTH < RPB)
        issue_load(ring[RR & (DEPTH - 1)], voff, pbase);

    constexpr int M = RR >> 2, Q = RR & 3;
    if constexpr (M - 0 >= 0 && M - 0 <= GSEG - 1) fma4(A[(M - 0) & 3], wr[Q +  0], v);
    if constexpr (M - 1 >= 0 && M - 1 <= GSEG - 1) fma4(A[(M - 1) & 3], wr[Q +  4], v);
    if constexpr (M - 2 >= 0 && M - 2 <= GSEG - 1) fma4(A[(M - 2) & 3], wr[Q +  8], v);
    if constexpr (M - 3 >= 0 && M - 3 <= GSEG - 1) fma4(A[(M - 3) & 3], wr[Q + 12], v);

    if constexpr (Q == 3 && M >= 3 && (M - 3) <= GSEG - 1)
        do_close(M - 3, A[(M - 3) & 3], vb, tid, Nw, wt, obase);
}

template<int RR> struct RowsT {
    static __device__ __forceinline__ void run(vf4 (&ring)[DEPTH], vf4 (&A)[4],
        unsigned& voff, const float* pbase, const float (&wr)[KT],
        float* vb, int tid, int Nw, const float (&wt)[KT], float* obase)
    {
        row_step<RR>(ring, A, voff, pbase, wr, vb, tid, Nw, wt, obase);
        RowsT<RR + 1>::run(ring, A, voff, pbase, wr, vb, tid, Nw, wt, obase);
    }
};
template<> struct RowsT<RPB> {
    static __device__ __forceinline__ void run(vf4 (&)[DEPTH], vf4 (&)[4],
        unsigned&, const float*, const float (&)[KT],
        float*, int, int, const float (&)[KT], float*) {}
};

// ---------------------------------------------------------------------------
// R11 (= R10 resubmitted after infra failure): edge-path de-serialization.
// R4 post-mortem: FETCH halved (259->138MB) but dur pinned 131->124us across
// 3 structurally different interiors -> invariant tail = edge path's
// fastc==false branch (256 serialized scalar gathers/thread, ~600 waves).
// Fix: mirrored column-index sets always span <=16 consecutive cols, so load
// ONE contiguous 16-float window at b = min(min_k ir[k], W-16) and FOLD
// duplicated taps into per-slot weights wf[j] = sum_{k: ir[k]==b+j} wt[k]
// (static cndmask-adds, pure VALU). Every edge thread now runs the identical
// contiguous fast path. Interior path byte-identical to R4.
// ---------------------------------------------------------------------------
__global__ __launch_bounds__(256, 4) void bicubic_fused(
    const float* __restrict__ x,    // [BC, H, W]
    const float* __restrict__ wh,   // [OH, KT]
    const int*   __restrict__ ih,   // [OH, KT]
    const float* __restrict__ ww,   // [OW, KT]
    const int*   __restrict__ iw,   // [OW, KT]
    float*       __restrict__ out)  // [BC, OH, OW]
{
    __shared__ float vbuf[2 * VSTRIDE];   // 8.3 KB ping-pong row buffers

    const int tid = threadIdx.x;
    const int bx  = blockIdx.x;
    const int by  = blockIdx.y;
    const int bc  = blockIdx.z;

    if (by < EDGE_YS) {
        // ---------------- edge path (branch-free, weight-folded) ----------
        const int idx = (by * 2 + bx) * 256 + tid;
        if (idx >= EDGE_TOT) return;

        int oh, ow;
        if (idx < EDGE_FULL) {
            int q = idx / OW;
            ow = idx - q * OW;
            oh = (q < 2) ? q : OH - 4 + q;
        } else {
            int t = idx - EDGE_FULL;
            int q = t & 3;
            oh = 2 + (t >> 2);
            ow = (q < 2) ? q : OW - 4 + q;
        }

        const float* __restrict__ img = x + (size_t)bc * ((size_t)H * W);

        float wt[KT];
        __builtin_memcpy(wt, ww + (size_t)ow * KT, sizeof(wt));
        int ir[KT];
        __builtin_memcpy(ir, iw + (size_t)ow * KT, sizeof(ir));

        // contiguous window base covering the (possibly mirrored) tap set
        int b = ir[0];
        #pragma unroll
        for (int k = 1; k < KT; ++k) b = (ir[k] < b) ? ir[k] : b;
        b = (b < W - KT) ? b : (W - KT);

        // fold taps into window-slot weights (all indices static)
        float wf[KT];
        #pragma unroll
        for (int j = 0; j < KT; ++j) {
            float s = 0.0f;
            #pragma unroll
            for (int k = 0; k < KT; ++k)
                s = (ir[k] == b + j) ? s + wt[k] : s;
            wf[j] = s;
        }

        float acc = 0.0f;
        #pragma unroll
        for (int kh = 0; kh < KT; ++kh) {
            const int   r = ih[oh * KT + kh];
            const float w = wh[oh * KT + kh];
            const float* row = img + (size_t)r * W + b;
            float v[KT];
            __builtin_memcpy(v, row, sizeof(v));
            float h0 = 0.f, h1 = 0.f;
            #pragma unroll
            for (int k = 0; k < KT; k += 2) {
                h0 = fmaf(v[k],     wf[k],     h0);
                h1 = fmaf(v[k + 1], wf[k + 1], h1);
            }
            acc = fmaf(w, h0 + h1, acc);
        }
        out[((size_t)bc * OH + oh) * OW + ow] = acc;
        return;
    }

    // ---------------- interior streaming path (identical to R4) ----------
    const int owb = bx ? 254 : 2;       // output-col tile base
    const int Nw  = bx ? 224 : 252;     // outputs in this tile
    const int c0  = 4 * owb - 8;        // staged col base: 0 / 1008
    const int seg = by - EDGE_YS;       // 0..18
    const int oh0 = 2 + GSEG * seg;     // 2..254
    const int r0  = 4 * oh0 - 6;        // 2..1010; r0+67 <= 1077 < H

    float wr[KT];
    __builtin_memcpy(wr, wh + (size_t)oh0 * KT, sizeof(wr));

    const int owc = (owb + tid < OW) ? (owb + tid) : (OW - 1);
    float wt[KT];
    __builtin_memcpy(wt, ww + (size_t)owc * KT, sizeof(wt));

    int c = c0 + 4 * tid;
    if (c > W - 4) c = W - 4;

    const float* pbase = x + ((size_t)bc * H + (size_t)r0) * W;
    unsigned voff = (unsigned)(4 * c);

    vf4 ring[DEPTH];
    vf4 A[4] = {vf4{0,0,0,0}, vf4{0,0,0,0}, vf4{0,0,0,0}, vf4{0,0,0,0}};

    #pragma unroll
    for (int i = 0; i < DEPTH; ++i) issue_load(ring[i], voff, pbase);

    float* obase = out + ((size_t)bc * OH + oh0) * OW + owb + tid;
    RowsT<0>::run(ring, A, voff, pbase, wr, vbuf, tid, Nw, wt, obase);
}

// ---------------------------------------------------------------------------
// Safety net for unexpected tap counts.
// ---------------------------------------------------------------------------
__global__ __launch_bounds__(256) void bicubic_generic(
    const float* __restrict__ x,
    const float* __restrict__ wh,
    const int*   __restrict__ ih,
    const float* __restrict__ ww,
    const int*   __restrict__ iw,
    float*       __restrict__ out,
    int Kh, int Kw, int total)
{
    int t = blockIdx.x * blockDim.x + threadIdx.x;
    if (t >= total) return;
    int ow = t % OW;
    int oh = (t / OW) % OH;
    int bc = t / (OW * OH);
    const float* img = x + (size_t)bc * ((size_t)H * W);
    float acc = 0.0f;
    for (int kh = 0; kh < Kh; ++kh) {
        const int   r = ih[oh * Kh + kh];
        const float w = wh[oh * Kh + kh];
        const float* row = img + (size_t)r * W;
        float h = 0.0f;
        for (int k = 0; k < Kw; ++k)
            h = fmaf(row[iw[ow * Kw + k]], ww[ow * Kw + k], h);
        acc = fmaf(w, h, acc);
    }
    out[t] = acc;
}

} // namespace

extern "C" void kernel_launch(void* const* d_in, const int* in_sizes, int n_in,
                              void* d_out, int out_size, void* d_ws, size_t ws_size,
                              hipStream_t stream) {
    const float* x  = (const float*)d_in[0];
    const float* wh = (const float*)d_in[1];
    const int*   ih = (const int*)d_in[2];
    const float* ww = (const float*)d_in[3];
    const int*   iw = (const int*)d_in[4];
    float*       out = (float*)d_out;

    const int BC = in_sizes[0] / (H * W);   // 24
    const int Kh = in_sizes[1] / OH;
    const int Kw = in_sizes[3] / OW;

    if (Kh == KT && Kw == KT) {
        dim3 grid(2, EDGE_YS + NSEG, BC);
        bicubic_fused<<<grid, 256, 0, stream>>>(x, wh, ih, ww, iw, out);
    } else {
        int total = BC * OH * OW;
        bicubic_generic<<<(total + 255) / 256, 256, 0, stream>>>(
            x, wh, ih, ww, iw, out, Kh, Kw, total);
    }
}

// Round 7
// 287.395 us; speedup vs baseline: 1.1297x; 1.0482x over previous
//
#include <hip/hip_runtime.h>

namespace {

constexpr int H  = 1080;
constexpr int W  = 1920;
constexpr int OH = 270;    // ceil(0.25 * 1080)
constexpr int OW = 480;    // ceil(0.25 * 1920)
constexpr int KT = 16;     // taps per output
constexpr int GSEG = 14;   // output rows per interior block; 266 = 19*14 exactly
constexpr int NSEG = 19;
constexpr int RPB  = 4 * GSEG + 12;   // 68 input rows streamed per block
constexpr int DEPTH = 8;              // load-ring depth (vmcnt-counted)
constexpr int VSTRIDE = 1032;         // LDS row stride in floats

constexpr int EDGE_FULL = 4 * OW;                    // 1920
constexpr int EDGE_TOT  = EDGE_FULL + (OH - 4) * 4;  // 2984
constexpr int EDGE_YS   = 6;   // 6 y-slices x 2 x-blocks x 256 = 3072 >= 2984

typedef float vf4 __attribute__((ext_vector_type(4)));

__device__ __forceinline__ void fma4(vf4& a, float w, const vf4& v) {
    #pragma unroll
    for (int i = 0; i < 4; ++i) a[i] = fmaf(w, v[i], a[i]);
}

// One streaming load: dwordx4 at (pbase SGPR-pair + voff), then bump voff by
// one image row (0x1e00 = 7680 B). Proven to assemble/run in R3/R4/R6.
__device__ __forceinline__ void issue_load(vf4& dst, unsigned& voff,
                                           const float* pbase) {
    asm volatile("global_load_dwordx4 %0, %1, %2\n\t"
                 "v_add_u32 %1, 0x1e00, %1"
                 : "=&v"(dst), "+v"(voff)
                 : "s"(pbase));
}

// Counted wait: allow N loads outstanding. sched_barrier stops the compiler
// from hoisting ring consumers above the wait (rule #18).
template<int N> __device__ __forceinline__ void wait_vmcnt() {
    static_assert(N >= 0 && N <= 7, "");
    if constexpr      (N == 0) asm volatile("s_waitcnt vmcnt(0)");
    else if constexpr (N == 1) asm volatile("s_waitcnt vmcnt(1)");
    else if constexpr (N == 2) asm volatile("s_waitcnt vmcnt(2)");
    else if constexpr (N == 3) asm volatile("s_waitcnt vmcnt(3)");
    else if constexpr (N == 4) asm volatile("s_waitcnt vmcnt(4)");
    else if constexpr (N == 5) asm volatile("s_waitcnt vmcnt(5)");
    else if constexpr (N == 6) asm volatile("s_waitcnt vmcnt(6)");
    else                       asm volatile("s_waitcnt vmcnt(7)");
    __builtin_amdgcn_sched_barrier(0);
}

// Close output row J: stage acc into LDS, raw barrier (NO vmcnt drain -> the
// global-load pipeline stays full), horizontal 16-tap, store.
// R12: wt is wave-uniform (SGPRs); LDS read split into two vf4 pairs so the
// VGPR transient is 8, not 16 (spill-proofing: total demand must stay < 64).
__device__ __forceinline__ void do_close(int J, vf4& acc, float* vb,
    int tid, int Nw, const float (&wt)[KT], float* obase)
{
    __builtin_memcpy(vb + (J & 1) * VSTRIDE + 4 * tid + 2, &acc, 16);
    acc = vf4{0.f, 0.f, 0.f, 0.f};
    asm volatile("s_waitcnt lgkmcnt(0)" ::: "memory");
    __builtin_amdgcn_s_barrier();
    if (tid < Nw) {
        const float* vbr = vb + (J & 1) * VSTRIDE + 4 * tid + 4;  // 16B-aligned
        vf4 v0, v1;
        float s0 = 0.f, s1 = 0.f;
        __builtin_memcpy(&v0, vbr + 0, 16);
        __builtin_memcpy(&v1, vbr + 4, 16);
        #pragma unroll
        for (int k = 0; k < 4; ++k) {
            s0 = fmaf(v0[k], wt[k],     s0);
            s1 = fmaf(v1[k], wt[k + 4], s1);
        }
        __builtin_memcpy(&v0, vbr + 8,  16);
        __builtin_memcpy(&v1, vbr + 12, 16);
        #pragma unroll
        for (int k = 0; k < 4; ++k) {
            s0 = fmaf(v0[k], wt[k + 8],  s0);
            s1 = fmaf(v1[k], wt[k + 12], s1);
        }
        obase[(size_t)J * OW] = s0 + s1;
    }
}

// One streamed input row RR (fully static indices).
template<int RR>
__device__ __forceinline__ void row_step(vf4 (&ring)[DEPTH], vf4 (&A)[4],
    unsigned& voff, const float* pbase, const float (&wr)[KT],
    float* vb, int tid, int Nw, const float (&wt)[KT], float* obase)
{
    constexpr int OUT = (RPB - 1 - RR) < 7 ? (RPB - 1 - RR) : 7;
    wait_vmcnt<OUT>();
    vf4 v = ring[RR & (DEPTH - 1)];
    if constexpr (RR + DEPTH < RPB)
        issue_load(ring[RR & (DEPTH - 1)], voff, pbase);

    constexpr int M = RR >> 2, Q = RR & 3;
    if constexpr (M - 0 >= 0 && M - 0 <= GSEG - 1) fma4(A[(M - 0) & 3], wr[Q +  0], v);
    if constexpr (M - 1 >= 0 && M - 1 <= GSEG - 1) fma4(A[(M - 1) & 3], wr[Q +  4], v);
    if constexpr (M - 2 >= 0 && M - 2 <= GSEG - 1) fma4(A[(M - 2) & 3], wr[Q +  8], v);
    if constexpr (M - 3 >= 0 && M - 3 <= GSEG - 1) fma4(A[(M - 3) & 3], wr[Q + 12], v);

    if constexpr (Q == 3 && M >= 3 && (M - 3) <= GSEG - 1)
        do_close(M - 3, A[(M - 3) & 3], vb, tid, Nw, wt, obase);
}

template<int RR> struct RowsT {
    static __device__ __forceinline__ void run(vf4 (&ring)[DEPTH], vf4 (&A)[4],
        unsigned& voff, const float* pbase, const float (&wr)[KT],
        float* vb, int tid, int Nw, const float (&wt)[KT], float* obase)
    {
        row_step<RR>(ring, A, voff, pbase, wr, vb, tid, Nw, wt, obase);
        RowsT<RR + 1>::run(ring, A, voff, pbase, wr, vb, tid, Nw, wt, obase);
    }
};
template<> struct RowsT<RPB> {
    static __device__ __forceinline__ void run(vf4 (&)[DEPTH], vf4 (&)[4],
        unsigned&, const float*, const float (&)[KT],
        float*, int, int, const float (&)[KT], float*) {}
};

// ---------------------------------------------------------------------------
// R12: interior spill-proofing. R6 decomposition: edge fix landed (bench
// 321->301, fused now < fill's 117us), interior ~100us remains at 1.3 TB/s
// while fill proves 6.7 TB/s needs only 9.5% occupancy -> waves internally
// serialized. R4's VGPR_Count=64 vs live-set demand ~75-80 (ring 32 + A 16
// + wt 16 + close vv 16) => allocator clamped + SPILLED; scratch ops are
// vmcnt-counted with compiler-inserted conservative waits -> ring drained
// every close. Fix: (a) wt is mathematically identical for ALL interior
// columns (weights = 0.25*cubic(0.25*(8.5-j)), ow-independent — same
// identity already used for wr across rows) -> load from block-uniform
// ww[owb] => SGPRs, frees 16 VGPRs; (b) close transient 16->8 via two
// sequential vf4-pair reads. New demand ~56 < 64: no spills.
// ---------------------------------------------------------------------------
__global__ __launch_bounds__(256, 4) void bicubic_fused(
    const float* __restrict__ x,    // [BC, H, W]
    const float* __restrict__ wh,   // [OH, KT]
    const int*   __restrict__ ih,   // [OH, KT]
    const float* __restrict__ ww,   // [OW, KT]
    const int*   __restrict__ iw,   // [OW, KT]
    float*       __restrict__ out)  // [BC, OH, OW]
{
    __shared__ float vbuf[2 * VSTRIDE];   // 8.3 KB ping-pong row buffers

    const int tid = threadIdx.x;
    const int bx  = blockIdx.x;
    const int by  = blockIdx.y;
    const int bc  = blockIdx.z;

    if (by < EDGE_YS) {
        // ---------------- edge path (branch-free, weight-folded; R6) ------
        const int idx = (by * 2 + bx) * 256 + tid;
        if (idx >= EDGE_TOT) return;

        int oh, ow;
        if (idx < EDGE_FULL) {
            int q = idx / OW;
            ow = idx - q * OW;
            oh = (q < 2) ? q : OH - 4 + q;
        } else {
            int t = idx - EDGE_FULL;
            int q = t & 3;
            oh = 2 + (t >> 2);
            ow = (q < 2) ? q : OW - 4 + q;
        }

        const float* __restrict__ img = x + (size_t)bc * ((size_t)H * W);

        float wt[KT];
        __builtin_memcpy(wt, ww + (size_t)ow * KT, sizeof(wt));
        int ir[KT];
        __builtin_memcpy(ir, iw + (size_t)ow * KT, sizeof(ir));

        // contiguous window base covering the (possibly mirrored) tap set
        int b = ir[0];
        #pragma unroll
        for (int k = 1; k < KT; ++k) b = (ir[k] < b) ? ir[k] : b;
        b = (b < W - KT) ? b : (W - KT);

        // fold taps into window-slot weights (all indices static)
        float wf[KT];
        #pragma unroll
        for (int j = 0; j < KT; ++j) {
            float s = 0.0f;
            #pragma unroll
            for (int k = 0; k < KT; ++k)
                s = (ir[k] == b + j) ? s + wt[k] : s;
            wf[j] = s;
        }

        float acc = 0.0f;
        #pragma unroll
        for (int kh = 0; kh < KT; ++kh) {
            const int   r = ih[oh * KT + kh];
            const float w = wh[oh * KT + kh];
            const float* row = img + (size_t)r * W + b;
            float v[KT];
            __builtin_memcpy(v, row, sizeof(v));
            float h0 = 0.f, h1 = 0.f;
            #pragma unroll
            for (int k = 0; k < KT; k += 2) {
                h0 = fmaf(v[k],     wf[k],     h0);
                h1 = fmaf(v[k + 1], wf[k + 1], h1);
            }
            acc = fmaf(w, h0 + h1, acc);
        }
        out[((size_t)bc * OH + oh) * OW + ow] = acc;
        return;
    }

    // ---------------- interior streaming path ----------------
    const int owb = bx ? 254 : 2;       // output-col tile base
    const int Nw  = bx ? 224 : 252;     // outputs in this tile
    const int c0  = 4 * owb - 8;        // staged col base: 0 / 1008
    const int seg = by - EDGE_YS;       // 0..18
    const int oh0 = 2 + GSEG * seg;     // 2..254
    const int r0  = 4 * oh0 - 6;        // 2..1010; r0+67 <= 1077 < H

    // vertical weights: identical for all interior rows -> SGPRs
    float wr[KT];
    __builtin_memcpy(wr, wh + (size_t)oh0 * KT, sizeof(wr));

    // horizontal weights: identical for ALL interior columns (ow in [2,477])
    // -> load from block-uniform ww[owb] => SGPRs, zero VGPR cost
    float wt[KT];
    __builtin_memcpy(wt, ww + (size_t)owb * KT, sizeof(wt));

    int c = c0 + 4 * tid;
    if (c > W - 4) c = W - 4;

    const float* pbase = x + ((size_t)bc * H + (size_t)r0) * W;
    unsigned voff = (unsigned)(4 * c);

    vf4 ring[DEPTH];
    vf4 A[4] = {vf4{0,0,0,0}, vf4{0,0,0,0}, vf4{0,0,0,0}, vf4{0,0,0,0}};

    #pragma unroll
    for (int i = 0; i < DEPTH; ++i) issue_load(ring[i], voff, pbase);

    float* obase = out + ((size_t)bc * OH + oh0) * OW + owb + tid;
    RowsT<0>::run(ring, A, voff, pbase, wr, vbuf, tid, Nw, wt, obase);
}

// ---------------------------------------------------------------------------
// Safety net for unexpected tap counts.
// ---------------------------------------------------------------------------
__global__ __launch_bounds__(256) void bicubic_generic(
    const float* __restrict__ x,
    const float* __restrict__ wh,
    const int*   __restrict__ ih,
    const float* __restrict__ ww,
    const int*   __restrict__ iw,
    float*       __restrict__ out,
    int Kh, int Kw, int total)
{
    int t = blockIdx.x * blockDim.x + threadIdx.x;
    if (t >= total) return;
    int ow = t % OW;
    int oh = (t / OW) % OH;
    int bc = t / (OW * OH);
    const float* img = x + (size_t)bc * ((size_t)H * W);
    float acc = 0.0f;
    for (int kh = 0; kh < Kh; ++kh) {
        const int   r = ih[oh * Kh + kh];
        const float w = wh[oh * Kh + kh];
        const float* row = img + (size_t)r * W;
        float h = 0.0f;
        for (int k = 0; k < Kw; ++k)
            h = fmaf(row[iw[ow * Kw + k]], ww[ow * Kw + k], h);
        acc = fmaf(w, h, acc);
    }
    out[t] = acc;
}

} // namespace

extern "C" void kernel_launch(void* const* d_in, const int* in_sizes, int n_in,
                              void* d_out, int out_size, void* d_ws, size_t ws_size,
                              hipStream_t stream) {
    const float* x  = (const float*)d_in[0];
    const float* wh = (const float*)d_in[1];
    const int*   ih = (const int*)d_in[2];
    const float* ww = (const float*)d_in[3];
    const int*   iw = (const int*)d_in[4];
    float*       out = (float*)d_out;

    const int BC = in_sizes[0] / (H * W);   // 24
    const int Kh = in_sizes[1] / OH;
    const int Kw = in_sizes[3] / OW;

    if (Kh == KT && Kw == KT) {
        dim3 grid(2, EDGE_YS + NSEG, BC);
        bicubic_fused<<<grid, 256, 0, stream>>>(x, wh, ih, ww, iw, out);
    } else {
        int total = BC * OH * OW;
        bicubic_generic<<<(total + 255) / 256, 256, 0, stream>>>(
            x, wh, ih, ww, iw, out, Kh, Kw, total);
    }
}